// Round 8
// baseline (237.912 us; speedup 1.0000x reference)
//
#include <hip/hip_runtime.h>
#include <hip/hip_bf16.h>
#include <stdint.h>

#define BATCH 4
#define SEQ   4096
#define DIM   2048
#define NFREQ 1025
#define NCPLX 1024
#define ROWS  (BATCH*SEQ)   // 16384

// fused chunk decomposition
#define SCH  16            // rows per block (sequential, cumsum in regs)
#define NSC  (SEQ/SCH)     // 256 chunks per batch
#define NSCG 16            // chunks per scan group
#define NGRP (NSC/NSCG)    // 16 groups

#define SPEC_STRIDE 257    // uint4 per row: 256 pair-packed + 1 extra (k=512)

typedef __bf16 bf16x8 __attribute__((ext_vector_type(8)));
typedef float  f32x4  __attribute__((ext_vector_type(4)));
typedef float  f32x16 __attribute__((ext_vector_type(16)));

__device__ __forceinline__ int drev4(int n) {  // reverse 5 base-4 digits of 10-bit n
  return ((n&3)<<8) | (((n>>2)&3)<<6) | (((n>>4)&3)<<4) | (((n>>6)&3)<<2) | ((n>>8)&3);
}
#define ZI(i) ((i) + ((i)>>4))   // LDS pad: every 16 float2 -> +1 (caps conflicts ~4-way)

__device__ __forceinline__ float2 cmulf(float2 a, float2 b) {
  return make_float2(a.x*b.x - a.y*b.y, a.x*b.y + a.y*b.x);
}

__device__ __forceinline__ unsigned short f2bf(float f) {
  union { float f; unsigned u; } v; v.f = f;
  unsigned r = v.u + 0x7fffu + ((v.u >> 16) & 1u);
  return (unsigned short)(r >> 16);
}
__device__ __forceinline__ unsigned packbf(float2 v) {
  return (unsigned)f2bf(v.x) | ((unsigned)f2bf(v.y) << 16);
}
__device__ __forceinline__ float2 unpackbf(unsigned u) {
  union { unsigned u; float f; } a, b;
  a.u = u << 16; b.u = u & 0xffff0000u;
  return make_float2(a.f, b.f);
}

// ---------------- radix-4 1024-pt in-place DIT, precomputed stage twiddles ----
template<int INV>
__device__ __forceinline__ void fft_stages_tw(float2* z, int tid, const float2* tw1) {
  { // stage q=1 (no twiddles)
    int b4 = tid*4;
    float2 x0=z[ZI(b4)], x1=z[ZI(b4+1)], x2=z[ZI(b4+2)], x3=z[ZI(b4+3)];
    float2 a = make_float2(x0.x+x2.x, x0.y+x2.y), b = make_float2(x0.x-x2.x, x0.y-x2.y);
    float2 c = make_float2(x1.x+x3.x, x1.y+x3.y), d = make_float2(x1.x-x3.x, x1.y-x3.y);
    z[ZI(b4)]   = make_float2(a.x+c.x, a.y+c.y);
    z[ZI(b4+2)] = make_float2(a.x-c.x, a.y-c.y);
    if (!INV) { z[ZI(b4+1)] = make_float2(b.x+d.y, b.y-d.x);
                z[ZI(b4+3)] = make_float2(b.x-d.y, b.y+d.x); }
    else      { z[ZI(b4+1)] = make_float2(b.x-d.y, b.y+d.x);
                z[ZI(b4+3)] = make_float2(b.x+d.y, b.y-d.x); }
  }
  __syncthreads();
#pragma unroll
  for (int s = 0; s < 4; ++s) {
    const int lq = 2 + 2*s;          // q = 4,16,64,256
    const int q  = 1 << lq;
    int j = tid & (q-1), g = tid >> lq;
    int base = (g << (lq+2)) + j;
    float2 w1 = tw1[s]; if (INV) w1.y = -w1.y;
    float2 w2 = cmulf(w1, w1), w3 = cmulf(w2, w1);
    float2 x0 = z[ZI(base)];
    float2 x1 = cmulf(z[ZI(base+q)],   w1);
    float2 x2 = cmulf(z[ZI(base+2*q)], w2);
    float2 x3 = cmulf(z[ZI(base+3*q)], w3);
    float2 a = make_float2(x0.x+x2.x, x0.y+x2.y), b = make_float2(x0.x-x2.x, x0.y-x2.y);
    float2 c = make_float2(x1.x+x3.x, x1.y+x3.y), d = make_float2(x1.x-x3.x, x1.y-x3.y);
    z[ZI(base)]     = make_float2(a.x+c.x, a.y+c.y);
    z[ZI(base+2*q)] = make_float2(a.x-c.x, a.y-c.y);
    if (!INV) { z[ZI(base+q)]   = make_float2(b.x+d.y, b.y-d.x);
                z[ZI(base+3*q)] = make_float2(b.x-d.y, b.y+d.x); }
    else      { z[ZI(base+q)]   = make_float2(b.x-d.y, b.y+d.x);
                z[ZI(base+3*q)] = make_float2(b.x+d.y, b.y-d.x); }
    __syncthreads();
  }
}

__device__ __forceinline__ void make_tw1(int tid, float2* tw1) {
#pragma unroll
  for (int s = 0; s < 4; ++s) {
    const int lq = 2 + 2*s;
    const int q  = 1 << lq;
    int j = tid & (q-1);
    float ang = -6.2831853071795864769f * (float)j / (float)(4*q);
    float sw, cw; __sincosf(ang, &sw, &cw);
    tw1[s] = make_float2(cw, sw);
  }
}

// ============ merged fwd_fused + wfft =========================================
__global__ __launch_bounds__(256) void fwd_wfft(const float* __restrict__ x,
                                                const float* __restrict__ w,
                                                const float* __restrict__ kvs,
                                                uint4* __restrict__ spec,
                                                float2* __restrict__ partial,
                                                unsigned short* __restrict__ H) {
  __shared__ float2 z[ZI(1023)+2];
  __shared__ __align__(16) unsigned short hrow[2048];
  const int tid = threadIdx.x;

  float2 tw1[4];
  make_tw1(tid, tw1);
  const int kA = tid, kB = tid + 256;
  int id0 = ZI(drev4(2*tid)),     id1 = ZI(drev4(2*tid+1));
  int id2 = ZI(drev4(2*tid+512)), id3 = ZI(drev4(2*tid+513));

  if (blockIdx.x >= BATCH*NSC) {
    // ---- wfft path: H[e,k] = alpha_k*Re(rfft(W[e]))[k]; H[e,1024+j] = (2/N)*Im[j]
    const int e = blockIdx.x - BATCH*NSC;
    float swA, cwA, swB, cwB;
    __sincosf(-3.14159265358979323846f * (float)kA / 1024.0f, &swA, &cwA);
    __sincosf(-3.14159265358979323846f * (float)kB / 1024.0f, &swB, &cwB);
    const float* wr = w + (size_t)e * DIM;
    float4 c0 = ((const float4*)wr)[tid];
    float4 c1 = ((const float4*)wr)[tid + 256];
    z[id0] = make_float2(c0.x, c0.y); z[id1] = make_float2(c0.z, c0.w);
    z[id2] = make_float2(c1.x, c1.y); z[id3] = make_float2(c1.z, c1.w);
    __syncthreads();
    fft_stages_tw<0>(z, tid, tw1);
    float2 ZkA = z[ZI(kA)], ZnA = z[ZI((NCPLX - kA) & (NCPLX-1))];
    float2 ZkB = z[ZI(kB)], ZnB = z[ZI(768 - tid)];
    float Er = 0.5f*(ZkA.x + ZnA.x), Ei = 0.5f*(ZkA.y - ZnA.y);
    float dr = 0.5f*(ZkA.x - ZnA.x), di = 0.5f*(ZkA.y + ZnA.y);
    float2 vA  = make_float2( Er + cwA*di + swA*dr,  Ei + swA*di - cwA*dr);
    float2 vAp = make_float2( Er - cwA*di - swA*dr, -Ei + swA*di - cwA*dr);
    float Fr = 0.5f*(ZkB.x + ZnB.x), Fi = 0.5f*(ZkB.y - ZnB.y);
    float er = 0.5f*(ZkB.x - ZnB.x), ei = 0.5f*(ZkB.y + ZnB.y);
    float2 vB  = make_float2( Fr + cwB*ei + swB*er,  Fi + swB*ei - cwB*er);
    float2 vBp = make_float2( Fr - cwB*ei - swB*er, -Fi + swB*ei - cwB*er);
    const float invN = 1.0f/2048.0f, twoN = 2.0f/2048.0f;
    float aA  = (tid == 0) ? invN : twoN;
    hrow[tid]        = f2bf(aA   * vA.x);
    hrow[1024 - tid] = f2bf(aA   * vAp.x);
    hrow[256 + tid]  = f2bf(twoN * vB.x);
    hrow[768 - tid]  = f2bf(twoN * vBp.x);
    if (tid) {
      hrow[1024 + tid] = f2bf(twoN * vA.y);
      hrow[2048 - tid] = f2bf(twoN * vAp.y);
    }
    hrow[1280 + tid] = f2bf(twoN * vB.y);
    hrow[1792 - tid] = f2bf(twoN * vBp.y);
    if (tid == 0) {
      float2 Z5 = z[ZI(512)];
      hrow[512]  = f2bf(twoN * Z5.x);
      hrow[1536] = f2bf(twoN * (-Z5.y));
    }
    __syncthreads();
    ((uint4*)(H + (size_t)e * DIM))[tid] = ((const uint4*)hrow)[tid];
    return;
  }

  // ---- fwd path ----
  const int sc = blockIdx.x & (NSC-1), b = blockIdx.x >> 8;
  float swA, cwA, swB, cwB;   // w = e^{-i pi k/1024}
  __sincosf(-3.14159265358979323846f * (float)kA / 1024.0f, &swA, &cwA);
  __sincosf(-3.14159265358979323846f * (float)kB / 1024.0f, &swB, &cwB);

  float2 sA={0,0}, sAp={0,0}, sB={0,0}, sBp={0,0}, s5={0,0};

  const size_t row0 = (size_t)b*SEQ + (size_t)sc*SCH;
  const float* xrow = x + row0*DIM;
  float4 c0 = ((const float4*)xrow)[tid];
  float4 c1 = ((const float4*)xrow)[tid + 256];

  for (int s = 0; s < SCH; ++s) {
    float4 n0f, n1f;
    if (s+1 < SCH) {
      const float* nx = xrow + (size_t)(s+1)*DIM;
      n0f = ((const float4*)nx)[tid]; n1f = ((const float4*)nx)[tid + 256];
    }
    z[id0] = make_float2(c0.x, c0.y); z[id1] = make_float2(c0.z, c0.w);
    z[id2] = make_float2(c1.x, c1.y); z[id3] = make_float2(c1.z, c1.w);
    __syncthreads();
    fft_stages_tw<0>(z, tid, tw1);
    float2 ZkA = z[ZI(kA)], ZnA = z[ZI((NCPLX - kA) & (NCPLX-1))];
    float2 ZkB = z[ZI(kB)], ZnB = z[ZI(768 - tid)];
    // pair unpack A: v[kA], v[1024-kA]
    float Er = 0.5f*(ZkA.x + ZnA.x), Ei = 0.5f*(ZkA.y - ZnA.y);
    float dr = 0.5f*(ZkA.x - ZnA.x), di = 0.5f*(ZkA.y + ZnA.y);
    float2 vA  = make_float2( Er + cwA*di + swA*dr,  Ei + swA*di - cwA*dr);
    float2 vAp = make_float2( Er - cwA*di - swA*dr, -Ei + swA*di - cwA*dr);
    // pair unpack B: v[kB], v[768-tid]
    float Fr = 0.5f*(ZkB.x + ZnB.x), Fi = 0.5f*(ZkB.y - ZnB.y);
    float er = 0.5f*(ZkB.x - ZnB.x), ei = 0.5f*(ZkB.y + ZnB.y);
    float2 vB  = make_float2( Fr + cwB*ei + swB*er,  Fi + swB*ei - cwB*er);
    float2 vBp = make_float2( Fr - cwB*ei - swB*er, -Fi + swB*ei - cwB*er);
    sA.x += vA.x;  sA.y += vA.y;   sAp.x += vAp.x; sAp.y += vAp.y;
    sB.x += vB.x;  sB.y += vB.y;   sBp.x += vBp.x; sBp.y += vBp.y;
    uint4* sprow = spec + (row0 + s) * SPEC_STRIDE;
    sprow[tid] = make_uint4(packbf(vA), packbf(vAp), packbf(vB), packbf(vBp));
    if (tid == 0) {
      float2 Z5 = z[ZI(512)];
      float2 v5 = make_float2(Z5.x, -Z5.y);
      s5.x += v5.x; s5.y += v5.y;
      ((unsigned*)(sprow + 256))[0] = packbf(v5);
    }
    __syncthreads();                                   // z free for next scatter
    c0 = n0f; c1 = n1f;
  }
  float2* pp = partial + ((size_t)(b*NSC + sc)) * NFREQ;
  float kvA = kvs[kA], kvAp = kvs[NCPLX - kA], kvB = kvs[kB], kvBp = kvs[768 - tid];
  pp[kA]          = make_float2(kvA*sA.x,  kvA*sA.y);
  pp[NCPLX - kA]  = make_float2(kvAp*sAp.x, kvAp*sAp.y);
  pp[kB]          = make_float2(kvB*sB.x,  kvB*sB.y);
  pp[768 - tid]   = make_float2(kvBp*sBp.x, kvBp*sBp.y);
  if (tid == 0) { float kv5 = kvs[512]; pp[512] = make_float2(kv5*s5.x, kv5*s5.y); }
}

// ============ scanA: exclusive scan within group; write RAW group totals ======
__global__ __launch_bounds__(256) void scanA(float2* __restrict__ partial,
                                             float2* __restrict__ gtot) {
  int kc = blockIdx.x % 5, g = (blockIdx.x / 5) % NGRP, b = blockIdx.x / (5*NGRP);
  int k = kc*256 + threadIdx.x;
  if (k >= NFREQ) return;
  float2* p = partial + ((size_t)(b*NSC + g*NSCG)) * NFREQ + k;
  float2 run = {0.f, 0.f};
#pragma unroll
  for (int i = 0; i < NSCG; ++i) {
    float2 t = p[(size_t)i*NFREQ];
    p[(size_t)i*NFREQ] = run;                          // exclusive within group
    run.x += t.x; run.y += t.y;
  }
  gtot[((size_t)(b*NGRP + g)) * NFREQ + k] = run;      // raw group total
}

// ============ inv_fused: inline group-prefix + cumsum-apply -> spectral G =====
__global__ __launch_bounds__(256) void inv_fused(const uint4* __restrict__ spec,
                                                 const float* __restrict__ kvs,
                                                 const float* __restrict__ qs_,
                                                 const float2* __restrict__ partial,
                                                 const float2* __restrict__ gtot,
                                                 unsigned short* __restrict__ G) {
  __shared__ __align__(16) unsigned short grow[2048];
  const int tid = threadIdx.x;
  const int sc = blockIdx.x & (NSC-1), b = blockIdx.x >> 8;
  const int kA = tid, kB = tid + 256;

  float ksA = kvs[kA], ksAp = kvs[NCPLX - kA], ksB = kvs[kB], ksBp = kvs[768 - tid];
  float qsA = qs_[kA], qsAp = qs_[NCPLX - kA], qsB = qs_[kB], qsBp = qs_[768 - tid];

  const float2* pp = partial + ((size_t)(b*NSC + sc)) * NFREQ;
  float2 CA  = pp[kA], CAp = pp[NCPLX-kA], CB = pp[kB], CBp = pp[768-tid];
  float ks5 = kvs[512], qs5 = qs_[512];
  float2 C5 = pp[512];
  // inline exclusive prefix over RAW group totals (replaces scanB kernel)
  {
    const int g = sc >> 4;
    const float2* gb = gtot + (size_t)b*NGRP*NFREQ;
    for (int gg = 0; gg < g; ++gg) {
      const float2* gr = gb + (size_t)gg*NFREQ;
      float2 a0 = gr[kA], a1 = gr[NCPLX-kA], a2 = gr[kB], a3 = gr[768-tid];
      CA.x += a0.x; CA.y += a0.y;   CAp.x += a1.x; CAp.y += a1.y;
      CB.x += a2.x; CB.y += a2.y;   CBp.x += a3.x; CBp.y += a3.y;
      if (tid == 0) { float2 a5 = gr[512]; C5.x += a5.x; C5.y += a5.y; }
    }
  }

  const size_t row0 = (size_t)b*SEQ + (size_t)sc*SCH;
  const uint4* sprow = spec + row0 * SPEC_STRIDE;
  uint4 sp = sprow[tid];
  unsigned spN = ((const unsigned*)(sprow + 256))[0];

  for (int s = 0; s < SCH; ++s) {
    uint4 spn; unsigned spNn;
    if (s+1 < SCH) {
      const uint4* nr = sprow + (size_t)(s+1) * SPEC_STRIDE;
      spn = nr[tid]; spNn = ((const unsigned*)(nr + 256))[0];
    }
    float2 vA = unpackbf(sp.x), vAp = unpackbf(sp.y);
    float2 vB = unpackbf(sp.z), vBp = unpackbf(sp.w);
    CA.x  += vA.x*ksA;   CA.y  += vA.y*ksA;
    CAp.x += vAp.x*ksAp; CAp.y += vAp.y*ksAp;
    CB.x  += vB.x*ksB;   CB.y  += vB.y*ksB;
    CBp.x += vBp.x*ksBp; CBp.y += vBp.y*ksBp;
    float2 qvA  = make_float2(qsA *(vA.x*CA.x  - vA.y*CA.y),  qsA *(vA.x*CA.y  + vA.y*CA.x));
    float2 qvAp = make_float2(qsAp*(vAp.x*CAp.x- vAp.y*CAp.y),qsAp*(vAp.x*CAp.y+ vAp.y*CAp.x));
    float2 qvB  = make_float2(qsB *(vB.x*CB.x  - vB.y*CB.y),  qsB *(vB.x*CB.y  + vB.y*CB.x));
    float2 qvBp = make_float2(qsBp*(vBp.x*CBp.x- vBp.y*CBp.y),qsBp*(vBp.x*CBp.y+ vBp.y*CBp.x));
    // scatter spectral row: real cols {t,1024-t,256+t,768-t}, imag cols 1024+k
    grow[tid]        = f2bf(qvA.x);
    grow[1024 - tid] = f2bf(qvAp.x);
    grow[256 + tid]  = f2bf(qvB.x);
    grow[768 - tid]  = f2bf(qvBp.x);
    if (tid) {
      grow[1024 + tid] = f2bf(qvA.y);
      grow[2048 - tid] = f2bf(qvAp.y);
    }
    grow[1280 + tid] = f2bf(qvB.y);
    grow[1792 - tid] = f2bf(qvBp.y);
    if (tid == 0) {
      float2 v5 = unpackbf(spN);
      C5.x += v5.x*ks5; C5.y += v5.y*ks5;
      grow[512]  = f2bf(qs5*(v5.x*C5.x - v5.y*C5.y));
      grow[1536] = f2bf(qs5*(v5.x*C5.y + v5.y*C5.x));
    }
    __syncthreads();
    ((uint4*)(G + (row0 + s) * DIM))[tid] = ((const uint4*)grow)[tid];
    __syncthreads();
    sp = spn; spN = spNn;
  }
}

// ============ 256x256 8-phase GEMM, 32x32x16 MFMA: C = A * B^T, bf16->fp32 =====
#define NKT (DIM/64)      // 32 K-tiles
#define NIT (NKT/2)       // 16 iterations of 2 K-tiles

#define BARX() do{ __builtin_amdgcn_s_barrier(); __builtin_amdgcn_sched_barrier(0); }while(0)
#define VMW(N) do{ asm volatile("s_waitcnt vmcnt(" #N ")" ::: "memory"); __builtin_amdgcn_sched_barrier(0); }while(0)

// A-frag: 2 m-tiles x 4 k-steps; row = wm*64 + mt*32 + (lane&31), k-byte = ks*32 + (lane>>5)*16
#define LOADA(B_, MH) do{ _Pragma("unroll") for (int mt_=0;mt_<2;++mt_) _Pragma("unroll") for (int ks_=0;ks_<4;++ks_){ \
    int rA_ = wm*64 + mt_*32 + l31; \
    aF[mt_][ks_] = *(const bf16x8*)(smem + ((B_)*2+(MH))*16384 + rA_*128 + ((ks_*32 + lhi2*16) ^ ((rA_&7)<<4))); } }while(0)

// B-frag: 4 k-steps; row (= H row = C col) = wn*32 + (lane&31)
#define LOADB(DST, B_, NH) do{ _Pragma("unroll") for (int ks_=0;ks_<4;++ks_){ \
    int rB_ = wn*32 + l31; \
    DST[ks_] = *(const bf16x8*)(smem + 65536 + ((B_)*2+(NH))*16384 + rB_*128 + ((ks_*32 + lhi2*16) ^ ((rB_&7)<<4))); } }while(0)

// 8 MFMA (32x32x16) for quadrant (MH,NH)
#define MM(MH, NH, BF) do{ __builtin_amdgcn_s_setprio(1); \
    _Pragma("unroll") for (int ks_=0;ks_<4;++ks_) _Pragma("unroll") for (int mt_=0;mt_<2;++mt_) \
      acc[MH][NH][mt_] = __builtin_amdgcn_mfma_f32_32x32x16_bf16(aF[mt_][ks_], BF[ks_], acc[MH][NH][mt_], 0, 0, 0); \
    __builtin_amdgcn_s_setprio(0); }while(0)

#define STAGEH(REG, B_, H_, GP, ROW0, KT) do{ _Pragma("unroll") for (int c_=0;c_<2;++c_){ \
    int ci_ = c_*512 + tid; int r_ = ci_>>3, sl_ = ci_&7; \
    const unsigned short* sp_ = (GP) + (size_t)((ROW0) + (H_)*128 + r_)*DIM + (KT) + ((sl_ ^ (r_&7))*8); \
    __builtin_amdgcn_global_load_lds((const __attribute__((address_space(1))) void*)sp_, \
      (__attribute__((address_space(3))) void*)(smem + (REG) + ((B_)*2+(H_))*16384 + ci_*16), 16, 0, 0); } }while(0)

__global__ __launch_bounds__(512, 2) void gemm256(const unsigned short* __restrict__ A,
                                                  const unsigned short* __restrict__ B,
                                                  float* __restrict__ C) {
  __shared__ __align__(16) char smem[131072];
  const int tid = threadIdx.x;
  const int lane = tid & 63;
  const int wid  = tid >> 6;
  const int wm = wid >> 2, wn = wid & 3;
  const int l31 = lane & 31, lhi2 = lane >> 5;

  // XCD-grouped swizzle: XCD j (= bid%8) owns bm in [8j, 8j+8) for all bn
  const int xj = blockIdx.x & 7, tt = blockIdx.x >> 3;
  const int bm = xj * 8 + (tt >> 3), bn = tt & 7;
  const int m0 = bm * 256, n0 = bn * 256;

  f32x16 acc[2][2][2] = {};          // [mh][nh][mt]
  bf16x8 aF[2][4], bF0[4], bF1[4];

  STAGEH(0,     0,0, A, m0, 0);  STAGEH(65536, 0,0, B, n0, 0);
  STAGEH(65536, 0,1, B, n0, 0);  STAGEH(0,     0,1, A, m0, 0);
  STAGEH(0,     1,0, A, m0, 64); STAGEH(65536, 1,0, B, n0, 64);
  STAGEH(65536, 1,1, B, n0, 64); STAGEH(0,     1,1, A, m0, 64);
  VMW(8);
  BARX();

#pragma unroll 1
  for (int j = 0; j < NIT-1; ++j) {
    const int kA = (2*j+2)*64, kB = (2*j+3)*64;
    LOADA(0,0); LOADB(bF0, 0,0);
    BARX(); MM(0,0,bF0); BARX();
    LOADB(bF1, 0,1);
    STAGEH(0, 0,0, A, m0, kA); STAGEH(65536, 0,0, B, n0, kA);
    BARX(); MM(0,1,bF1); BARX();
    LOADA(0,1);
    STAGEH(65536, 0,1, B, n0, kA);
    BARX(); MM(1,0,bF0); BARX();
    STAGEH(0, 0,1, A, m0, kA);
    VMW(8);
    BARX(); MM(1,1,bF1); BARX();
    LOADA(1,0); LOADB(bF0, 1,0);
    BARX(); MM(0,0,bF0); BARX();
    LOADB(bF1, 1,1);
    STAGEH(0, 1,0, A, m0, kB); STAGEH(65536, 1,0, B, n0, kB);
    BARX(); MM(0,1,bF1); BARX();
    LOADA(1,1);
    STAGEH(65536, 1,1, B, n0, kB);
    BARX(); MM(1,0,bF0); BARX();
    STAGEH(0, 1,1, A, m0, kB);
    VMW(8);
    BARX(); MM(1,1,bF1); BARX();
  }
  LOADA(0,0); LOADB(bF0, 0,0);
  BARX(); MM(0,0,bF0); BARX();
  LOADB(bF1, 0,1);
  BARX(); MM(0,1,bF1); BARX();
  LOADA(0,1);
  BARX(); MM(1,0,bF0); BARX();
  VMW(0);
  BARX(); MM(1,1,bF1); BARX();
  LOADA(1,0); LOADB(bF0, 1,0);
  BARX(); MM(0,0,bF0); BARX();
  LOADB(bF1, 1,1);
  BARX(); MM(0,1,bF1); BARX();
  LOADA(1,1);
  BARX(); MM(1,0,bF0); BARX();
  BARX(); MM(1,1,bF1); BARX();

  // epilogue: D layout (32x32): col = lane&31, row = (reg&3) + 8*(reg>>2) + 4*(lane>>5)
#pragma unroll
  for (int mh = 0; mh < 2; ++mh)
#pragma unroll
    for (int nh = 0; nh < 2; ++nh)
#pragma unroll
      for (int mt_ = 0; mt_ < 2; ++mt_) {
        const int colc = n0 + nh*128 + wn*32 + l31;
        const int rowb = m0 + mh*128 + wm*64 + mt_*32 + 4*lhi2;
#pragma unroll
        for (int reg = 0; reg < 16; ++reg) {
          int row = rowb + (reg&3) + 8*(reg>>2);
          C[(size_t)row*DIM + colc] = acc[mh][nh][mt_][reg];
        }
      }
}

// ---------------- launch -------------------------------------------------------
extern "C" void kernel_launch(void* const* d_in, const int* in_sizes, int n_in,
                              void* d_out, int out_size, void* d_ws, size_t ws_size,
                              hipStream_t stream) {
  const float* x    = (const float*)d_in[0];
  const float* qry  = (const float*)d_in[1];
  const float* kvs  = (const float*)d_in[2];
  const float* wout = (const float*)d_in[3];
  float* out = (float*)d_out;

  char* ws = (char*)d_ws;
  size_t off = 0;
  uint4* spec = (uint4*)(ws + off);                     // 67.4 MB
  off += (size_t)ROWS * SPEC_STRIDE * sizeof(uint4);
  off = (off + 255) & ~(size_t)255;
  unsigned short* G = (unsigned short*)(ws + off);      // 67 MB (spectral A)
  off += (size_t)ROWS * DIM * sizeof(unsigned short);
  off = (off + 255) & ~(size_t)255;
  unsigned short* H = (unsigned short*)(ws + off);      // 8.4 MB (spectral W)
  off += (size_t)DIM * DIM * sizeof(unsigned short);
  off = (off + 255) & ~(size_t)255;
  float2* partial = (float2*)(ws + off);                // 8.4 MB
  off += (size_t)BATCH * NSC * NFREQ * sizeof(float2);
  off = (off + 255) & ~(size_t)255;
  float2* gtot = (float2*)(ws + off);                   // 0.5 MB (raw group totals)
  off += (size_t)BATCH * NGRP * NFREQ * sizeof(float2);

  hipLaunchKernelGGL(fwd_wfft,  dim3(BATCH*NSC + DIM),   dim3(256), 0, stream, x, wout, kvs, spec, partial, H);
  hipLaunchKernelGGL(scanA,     dim3(BATCH*NGRP*5),      dim3(256), 0, stream, partial, gtot);
  hipLaunchKernelGGL(inv_fused, dim3(BATCH*NSC),         dim3(256), 0, stream, spec, kvs, qry, partial, gtot, G);
  hipLaunchKernelGGL(gemm256,   dim3((ROWS/256)*(DIM/256)), dim3(512), 0, stream, G, H, out);
}

// Round 9
// 222.101 us; speedup vs baseline: 1.0712x; 1.0712x over previous
//
#include <hip/hip_runtime.h>
#include <hip/hip_bf16.h>
#include <stdint.h>

#define BATCH 4
#define SEQ   4096
#define DIM   2048
#define NFREQ 1025
#define NCPLX 1024
#define ROWS  (BATCH*SEQ)   // 16384

// fused chunk decomposition
#define SCH  16            // rows per block (sequential, cumsum in regs)
#define NSC  (SEQ/SCH)     // 256 chunks per batch
#define NSCG 16            // chunks per scan group
#define NGRP (NSC/NSCG)    // 16 groups

#define SPEC_STRIDE 257    // uint4 per row: 256 pair-packed + 1 extra (k=512)

typedef __bf16 bf16x8 __attribute__((ext_vector_type(8)));
typedef float  f32x4  __attribute__((ext_vector_type(4)));

__device__ __forceinline__ int drev4(int n) {  // reverse 5 base-4 digits of 10-bit n
  return ((n&3)<<8) | (((n>>2)&3)<<6) | (((n>>4)&3)<<4) | (((n>>6)&3)<<2) | ((n>>8)&3);
}
#define ZI(i) ((i) + ((i)>>4))   // LDS pad: every 16 float2 -> +1 (caps conflicts ~4-way)

__device__ __forceinline__ float2 cmulf(float2 a, float2 b) {
  return make_float2(a.x*b.x - a.y*b.y, a.x*b.y + a.y*b.x);
}

__device__ __forceinline__ unsigned short f2bf(float f) {
  union { float f; unsigned u; } v; v.f = f;
  unsigned r = v.u + 0x7fffu + ((v.u >> 16) & 1u);
  return (unsigned short)(r >> 16);
}
__device__ __forceinline__ unsigned packbf(float2 v) {
  return (unsigned)f2bf(v.x) | ((unsigned)f2bf(v.y) << 16);
}
__device__ __forceinline__ float2 unpackbf(unsigned u) {
  union { unsigned u; float f; } a, b;
  a.u = u << 16; b.u = u & 0xffff0000u;
  return make_float2(a.f, b.f);
}

// ---------------- radix-4 1024-pt in-place DIT, precomputed stage twiddles ----
template<int INV>
__device__ __forceinline__ void fft_stages_tw(float2* z, int tid, const float2* tw1) {
  { // stage q=1 (no twiddles)
    int b4 = tid*4;
    float2 x0=z[ZI(b4)], x1=z[ZI(b4+1)], x2=z[ZI(b4+2)], x3=z[ZI(b4+3)];
    float2 a = make_float2(x0.x+x2.x, x0.y+x2.y), b = make_float2(x0.x-x2.x, x0.y-x2.y);
    float2 c = make_float2(x1.x+x3.x, x1.y+x3.y), d = make_float2(x1.x-x3.x, x1.y-x3.y);
    z[ZI(b4)]   = make_float2(a.x+c.x, a.y+c.y);
    z[ZI(b4+2)] = make_float2(a.x-c.x, a.y-c.y);
    if (!INV) { z[ZI(b4+1)] = make_float2(b.x+d.y, b.y-d.x);
                z[ZI(b4+3)] = make_float2(b.x-d.y, b.y+d.x); }
    else      { z[ZI(b4+1)] = make_float2(b.x-d.y, b.y+d.x);
                z[ZI(b4+3)] = make_float2(b.x+d.y, b.y-d.x); }
  }
  __syncthreads();
#pragma unroll
  for (int s = 0; s < 4; ++s) {
    const int lq = 2 + 2*s;          // q = 4,16,64,256
    const int q  = 1 << lq;
    int j = tid & (q-1), g = tid >> lq;
    int base = (g << (lq+2)) + j;
    float2 w1 = tw1[s]; if (INV) w1.y = -w1.y;
    float2 w2 = cmulf(w1, w1), w3 = cmulf(w2, w1);
    float2 x0 = z[ZI(base)];
    float2 x1 = cmulf(z[ZI(base+q)],   w1);
    float2 x2 = cmulf(z[ZI(base+2*q)], w2);
    float2 x3 = cmulf(z[ZI(base+3*q)], w3);
    float2 a = make_float2(x0.x+x2.x, x0.y+x2.y), b = make_float2(x0.x-x2.x, x0.y-x2.y);
    float2 c = make_float2(x1.x+x3.x, x1.y+x3.y), d = make_float2(x1.x-x3.x, x1.y-x3.y);
    z[ZI(base)]     = make_float2(a.x+c.x, a.y+c.y);
    z[ZI(base+2*q)] = make_float2(a.x-c.x, a.y-c.y);
    if (!INV) { z[ZI(base+q)]   = make_float2(b.x+d.y, b.y-d.x);
                z[ZI(base+3*q)] = make_float2(b.x-d.y, b.y+d.x); }
    else      { z[ZI(base+q)]   = make_float2(b.x-d.y, b.y+d.x);
                z[ZI(base+3*q)] = make_float2(b.x+d.y, b.y-d.x); }
    __syncthreads();
  }
}

__device__ __forceinline__ void make_tw1(int tid, float2* tw1) {
#pragma unroll
  for (int s = 0; s < 4; ++s) {
    const int lq = 2 + 2*s;
    const int q  = 1 << lq;
    int j = tid & (q-1);
    float ang = -6.2831853071795864769f * (float)j / (float)(4*q);
    float sw, cw; __sincosf(ang, &sw, &cw);
    tw1[s] = make_float2(cw, sw);
  }
}

// ============ merged fwd_fused + wfft =========================================
__global__ __launch_bounds__(256) void fwd_wfft(const float* __restrict__ x,
                                                const float* __restrict__ w,
                                                const float* __restrict__ kvs,
                                                uint4* __restrict__ spec,
                                                float2* __restrict__ partial,
                                                unsigned short* __restrict__ H) {
  __shared__ float2 z[ZI(1023)+2];
  __shared__ __align__(16) unsigned short hrow[2048];
  const int tid = threadIdx.x;

  float2 tw1[4];
  make_tw1(tid, tw1);
  const int kA = tid, kB = tid + 256;
  int id0 = ZI(drev4(2*tid)),     id1 = ZI(drev4(2*tid+1));
  int id2 = ZI(drev4(2*tid+512)), id3 = ZI(drev4(2*tid+513));

  if (blockIdx.x >= BATCH*NSC) {
    // ---- wfft path: H[e,k] = alpha_k*Re(rfft(W[e]))[k]; H[e,1024+j] = (2/N)*Im[j]
    const int e = blockIdx.x - BATCH*NSC;
    float swA, cwA, swB, cwB;
    __sincosf(-3.14159265358979323846f * (float)kA / 1024.0f, &swA, &cwA);
    __sincosf(-3.14159265358979323846f * (float)kB / 1024.0f, &swB, &cwB);
    const float* wr = w + (size_t)e * DIM;
    float4 c0 = ((const float4*)wr)[tid];
    float4 c1 = ((const float4*)wr)[tid + 256];
    z[id0] = make_float2(c0.x, c0.y); z[id1] = make_float2(c0.z, c0.w);
    z[id2] = make_float2(c1.x, c1.y); z[id3] = make_float2(c1.z, c1.w);
    __syncthreads();
    fft_stages_tw<0>(z, tid, tw1);
    float2 ZkA = z[ZI(kA)], ZnA = z[ZI((NCPLX - kA) & (NCPLX-1))];
    float2 ZkB = z[ZI(kB)], ZnB = z[ZI(768 - tid)];
    float Er = 0.5f*(ZkA.x + ZnA.x), Ei = 0.5f*(ZkA.y - ZnA.y);
    float dr = 0.5f*(ZkA.x - ZnA.x), di = 0.5f*(ZkA.y + ZnA.y);
    float2 vA  = make_float2( Er + cwA*di + swA*dr,  Ei + swA*di - cwA*dr);
    float2 vAp = make_float2( Er - cwA*di - swA*dr, -Ei + swA*di - cwA*dr);
    float Fr = 0.5f*(ZkB.x + ZnB.x), Fi = 0.5f*(ZkB.y - ZnB.y);
    float er = 0.5f*(ZkB.x - ZnB.x), ei = 0.5f*(ZkB.y + ZnB.y);
    float2 vB  = make_float2( Fr + cwB*ei + swB*er,  Fi + swB*ei - cwB*er);
    float2 vBp = make_float2( Fr - cwB*ei - swB*er, -Fi + swB*ei - cwB*er);
    const float invN = 1.0f/2048.0f, twoN = 2.0f/2048.0f;
    float aA  = (tid == 0) ? invN : twoN;
    hrow[tid]        = f2bf(aA   * vA.x);
    hrow[1024 - tid] = f2bf(aA   * vAp.x);
    hrow[256 + tid]  = f2bf(twoN * vB.x);
    hrow[768 - tid]  = f2bf(twoN * vBp.x);
    if (tid) {
      hrow[1024 + tid] = f2bf(twoN * vA.y);
      hrow[2048 - tid] = f2bf(twoN * vAp.y);
    }
    hrow[1280 + tid] = f2bf(twoN * vB.y);
    hrow[1792 - tid] = f2bf(twoN * vBp.y);
    if (tid == 0) {
      float2 Z5 = z[ZI(512)];
      hrow[512]  = f2bf(twoN * Z5.x);
      hrow[1536] = f2bf(twoN * (-Z5.y));
    }
    __syncthreads();
    ((uint4*)(H + (size_t)e * DIM))[tid] = ((const uint4*)hrow)[tid];
    return;
  }

  // ---- fwd path ----
  const int sc = blockIdx.x & (NSC-1), b = blockIdx.x >> 8;
  float swA, cwA, swB, cwB;   // w = e^{-i pi k/1024}
  __sincosf(-3.14159265358979323846f * (float)kA / 1024.0f, &swA, &cwA);
  __sincosf(-3.14159265358979323846f * (float)kB / 1024.0f, &swB, &cwB);

  float2 sA={0,0}, sAp={0,0}, sB={0,0}, sBp={0,0}, s5={0,0};

  const size_t row0 = (size_t)b*SEQ + (size_t)sc*SCH;
  const float* xrow = x + row0*DIM;
  float4 c0 = ((const float4*)xrow)[tid];
  float4 c1 = ((const float4*)xrow)[tid + 256];

  for (int s = 0; s < SCH; ++s) {
    float4 n0f, n1f;
    if (s+1 < SCH) {
      const float* nx = xrow + (size_t)(s+1)*DIM;
      n0f = ((const float4*)nx)[tid]; n1f = ((const float4*)nx)[tid + 256];
    }
    z[id0] = make_float2(c0.x, c0.y); z[id1] = make_float2(c0.z, c0.w);
    z[id2] = make_float2(c1.x, c1.y); z[id3] = make_float2(c1.z, c1.w);
    __syncthreads();
    fft_stages_tw<0>(z, tid, tw1);
    float2 ZkA = z[ZI(kA)], ZnA = z[ZI((NCPLX - kA) & (NCPLX-1))];
    float2 ZkB = z[ZI(kB)], ZnB = z[ZI(768 - tid)];
    // pair unpack A: v[kA], v[1024-kA]
    float Er = 0.5f*(ZkA.x + ZnA.x), Ei = 0.5f*(ZkA.y - ZnA.y);
    float dr = 0.5f*(ZkA.x - ZnA.x), di = 0.5f*(ZkA.y + ZnA.y);
    float2 vA  = make_float2( Er + cwA*di + swA*dr,  Ei + swA*di - cwA*dr);
    float2 vAp = make_float2( Er - cwA*di - swA*dr, -Ei + swA*di - cwA*dr);
    // pair unpack B: v[kB], v[768-tid]
    float Fr = 0.5f*(ZkB.x + ZnB.x), Fi = 0.5f*(ZkB.y - ZnB.y);
    float er = 0.5f*(ZkB.x - ZnB.x), ei = 0.5f*(ZkB.y + ZnB.y);
    float2 vB  = make_float2( Fr + cwB*ei + swB*er,  Fi + swB*ei - cwB*er);
    float2 vBp = make_float2( Fr - cwB*ei - swB*er, -Fi + swB*ei - cwB*er);
    sA.x += vA.x;  sA.y += vA.y;   sAp.x += vAp.x; sAp.y += vAp.y;
    sB.x += vB.x;  sB.y += vB.y;   sBp.x += vBp.x; sBp.y += vBp.y;
    uint4* sprow = spec + (row0 + s) * SPEC_STRIDE;
    sprow[tid] = make_uint4(packbf(vA), packbf(vAp), packbf(vB), packbf(vBp));
    if (tid == 0) {
      float2 Z5 = z[ZI(512)];
      float2 v5 = make_float2(Z5.x, -Z5.y);
      s5.x += v5.x; s5.y += v5.y;
      ((unsigned*)(sprow + 256))[0] = packbf(v5);
    }
    __syncthreads();                                   // z free for next scatter
    c0 = n0f; c1 = n1f;
  }
  float2* pp = partial + ((size_t)(b*NSC + sc)) * NFREQ;
  float kvA = kvs[kA], kvAp = kvs[NCPLX - kA], kvB = kvs[kB], kvBp = kvs[768 - tid];
  pp[kA]          = make_float2(kvA*sA.x,  kvA*sA.y);
  pp[NCPLX - kA]  = make_float2(kvAp*sAp.x, kvAp*sAp.y);
  pp[kB]          = make_float2(kvB*sB.x,  kvB*sB.y);
  pp[768 - tid]   = make_float2(kvBp*sBp.x, kvBp*sBp.y);
  if (tid == 0) { float kv5 = kvs[512]; pp[512] = make_float2(kv5*s5.x, kv5*s5.y); }
}

// ============ scanA: exclusive scan within group; write RAW group totals ======
__global__ __launch_bounds__(256) void scanA(float2* __restrict__ partial,
                                             float2* __restrict__ gtot) {
  int kc = blockIdx.x % 5, g = (blockIdx.x / 5) % NGRP, b = blockIdx.x / (5*NGRP);
  int k = kc*256 + threadIdx.x;
  if (k >= NFREQ) return;
  float2* p = partial + ((size_t)(b*NSC + g*NSCG)) * NFREQ + k;
  float2 run = {0.f, 0.f};
#pragma unroll
  for (int i = 0; i < NSCG; ++i) {
    float2 t = p[(size_t)i*NFREQ];
    p[(size_t)i*NFREQ] = run;                          // exclusive within group
    run.x += t.x; run.y += t.y;
  }
  gtot[((size_t)(b*NGRP + g)) * NFREQ + k] = run;      // raw group total
}

// ============ inv_fused: inline group-prefix + cumsum-apply -> spectral G =====
__global__ __launch_bounds__(256) void inv_fused(const uint4* __restrict__ spec,
                                                 const float* __restrict__ kvs,
                                                 const float* __restrict__ qs_,
                                                 const float2* __restrict__ partial,
                                                 const float2* __restrict__ gtot,
                                                 unsigned short* __restrict__ G) {
  __shared__ __align__(16) unsigned short grow[2][2048];   // double-buffered
  const int tid = threadIdx.x;
  const int sc = blockIdx.x & (NSC-1), b = blockIdx.x >> 8;
  const int kA = tid, kB = tid + 256;

  float ksA = kvs[kA], ksAp = kvs[NCPLX - kA], ksB = kvs[kB], ksBp = kvs[768 - tid];
  float qsA = qs_[kA], qsAp = qs_[NCPLX - kA], qsB = qs_[kB], qsBp = qs_[768 - tid];

  const float2* pp = partial + ((size_t)(b*NSC + sc)) * NFREQ;
  float2 CA  = pp[kA], CAp = pp[NCPLX-kA], CB = pp[kB], CBp = pp[768-tid];
  float ks5 = kvs[512], qs5 = qs_[512];
  float2 C5 = pp[512];
  // inline exclusive prefix over RAW group totals (replaces scanB kernel)
  {
    const int g = sc >> 4;
    const float2* gb = gtot + (size_t)b*NGRP*NFREQ;
    for (int gg = 0; gg < g; ++gg) {
      const float2* gr = gb + (size_t)gg*NFREQ;
      float2 a0 = gr[kA], a1 = gr[NCPLX-kA], a2 = gr[kB], a3 = gr[768-tid];
      CA.x += a0.x; CA.y += a0.y;   CAp.x += a1.x; CAp.y += a1.y;
      CB.x += a2.x; CB.y += a2.y;   CBp.x += a3.x; CBp.y += a3.y;
      if (tid == 0) { float2 a5 = gr[512]; C5.x += a5.x; C5.y += a5.y; }
    }
  }

  const size_t row0 = (size_t)b*SEQ + (size_t)sc*SCH;
  const uint4* sprow = spec + row0 * SPEC_STRIDE;
  uint4 sp = sprow[tid];
  unsigned spN = ((const unsigned*)(sprow + 256))[0];

  for (int s = 0; s < SCH; ++s) {
    uint4 spn; unsigned spNn;
    if (s+1 < SCH) {
      const uint4* nr = sprow + (size_t)(s+1) * SPEC_STRIDE;
      spn = nr[tid]; spNn = ((const unsigned*)(nr + 256))[0];
    }
    unsigned short* gw = grow[s & 1];
    float2 vA = unpackbf(sp.x), vAp = unpackbf(sp.y);
    float2 vB = unpackbf(sp.z), vBp = unpackbf(sp.w);
    CA.x  += vA.x*ksA;   CA.y  += vA.y*ksA;
    CAp.x += vAp.x*ksAp; CAp.y += vAp.y*ksAp;
    CB.x  += vB.x*ksB;   CB.y  += vB.y*ksB;
    CBp.x += vBp.x*ksBp; CBp.y += vBp.y*ksBp;
    float2 qvA  = make_float2(qsA *(vA.x*CA.x  - vA.y*CA.y),  qsA *(vA.x*CA.y  + vA.y*CA.x));
    float2 qvAp = make_float2(qsAp*(vAp.x*CAp.x- vAp.y*CAp.y),qsAp*(vAp.x*CAp.y+ vAp.y*CAp.x));
    float2 qvB  = make_float2(qsB *(vB.x*CB.x  - vB.y*CB.y),  qsB *(vB.x*CB.y  + vB.y*CB.x));
    float2 qvBp = make_float2(qsBp*(vBp.x*CBp.x- vBp.y*CBp.y),qsBp*(vBp.x*CBp.y+ vBp.y*CBp.x));
    // scatter spectral row: real cols {t,1024-t,256+t,768-t}, imag cols 1024+k
    gw[tid]        = f2bf(qvA.x);
    gw[1024 - tid] = f2bf(qvAp.x);
    gw[256 + tid]  = f2bf(qvB.x);
    gw[768 - tid]  = f2bf(qvBp.x);
    if (tid) {
      gw[1024 + tid] = f2bf(qvA.y);
      gw[2048 - tid] = f2bf(qvAp.y);
    }
    gw[1280 + tid] = f2bf(qvB.y);
    gw[1792 - tid] = f2bf(qvBp.y);
    if (tid == 0) {
      float2 v5 = unpackbf(spN);
      C5.x += v5.x*ks5; C5.y += v5.y*ks5;
      gw[512]  = f2bf(qs5*(v5.x*C5.x - v5.y*C5.y));
      gw[1536] = f2bf(qs5*(v5.x*C5.y + v5.y*C5.x));
    }
    __syncthreads();
    ((uint4*)(G + (row0 + s) * DIM))[tid] = ((const uint4*)gw)[tid];
    // no trailing barrier: next iteration scatters into the other buffer
    sp = spn; spN = spNn;
  }
}

// ============ 256x256 8-phase GEMM: C[M,N] = A[M,K] * B[N,K]^T, bf16->fp32 =====
#define NKT (DIM/64)      // 32 K-tiles
#define NIT (NKT/2)       // 16 iterations of 2 K-tiles

#define BAR()  __builtin_amdgcn_s_barrier()
#define VMW(N) do{ asm volatile("s_waitcnt vmcnt(" #N ")" ::: "memory"); __builtin_amdgcn_sched_barrier(0); }while(0)

#define LOADA(B_, MH) do{ _Pragma("unroll") for (int m_=0;m_<4;++m_) _Pragma("unroll") for (int kk_=0;kk_<2;++kk_){ \
    int rA_ = wm*64 + m_*16 + l15; \
    aF[m_][kk_] = *(const bf16x8*)(smem + ((B_)*2+(MH))*16384 + rA_*128 + ((kk_*64 + lhi*16) ^ ((rA_&7)<<4))); } }while(0)

#define LOADB(DST, B_, NH) do{ _Pragma("unroll") for (int n_=0;n_<2;++n_) _Pragma("unroll") for (int kk_=0;kk_<2;++kk_){ \
    int rB_ = wn*32 + n_*16 + l15; \
    DST[n_][kk_] = *(const bf16x8*)(smem + 65536 + ((B_)*2+(NH))*16384 + rB_*128 + ((kk_*64 + lhi*16) ^ ((rB_&7)<<4))); } }while(0)

#define MM(MH, NH, BF) do{ __builtin_amdgcn_s_setprio(1); \
    _Pragma("unroll") for (int kk_=0;kk_<2;++kk_) _Pragma("unroll") for (int m_=0;m_<4;++m_) _Pragma("unroll") for (int n_=0;n_<2;++n_) \
      acc[MH][NH][m_][n_] = __builtin_amdgcn_mfma_f32_16x16x32_bf16(aF[m_][kk_], BF[n_][kk_], acc[MH][NH][m_][n_], 0, 0, 0); \
    __builtin_amdgcn_s_setprio(0); }while(0)

#define STAGEH(REG, B_, H_, GP, ROW0, KT) do{ _Pragma("unroll") for (int c_=0;c_<2;++c_){ \
    int ci_ = c_*512 + tid; int r_ = ci_>>3, sl_ = ci_&7; \
    const unsigned short* sp_ = (GP) + (size_t)((ROW0) + (H_)*128 + r_)*DIM + (KT) + ((sl_ ^ (r_&7))*8); \
    __builtin_amdgcn_global_load_lds((const __attribute__((address_space(1))) void*)sp_, \
      (__attribute__((address_space(3))) void*)(smem + (REG) + ((B_)*2+(H_))*16384 + ci_*16), 16, 0, 0); } }while(0)

__global__ __launch_bounds__(512, 2) void gemm256(const unsigned short* __restrict__ A,
                                                  const unsigned short* __restrict__ B,
                                                  float* __restrict__ C) {
  __shared__ __align__(16) char smem[131072];
  const int tid = threadIdx.x;
  const int lane = tid & 63;
  const int wid  = tid >> 6;
  const int wm = wid >> 2, wn = wid & 3;
  const int l15 = lane & 15, lhi = lane >> 4;

  // XCD-grouped swizzle: XCD j (= bid%8) owns bm in [8j, 8j+8) for all bn
  const int xj = blockIdx.x & 7, tt = blockIdx.x >> 3;
  const int bm = xj * 8 + (tt >> 3), bn = tt & 7;
  const int m0 = bm * 256, n0 = bn * 256;

  f32x4 acc[2][2][4][2] = {};
  bf16x8 aF[4][2], bF0[2][2], bF1[2][2];

  STAGEH(0,     0,0, A, m0, 0);  STAGEH(65536, 0,0, B, n0, 0);
  STAGEH(65536, 0,1, B, n0, 0);  STAGEH(0,     0,1, A, m0, 0);
  STAGEH(0,     1,0, A, m0, 64); STAGEH(65536, 1,0, B, n0, 64);
  STAGEH(65536, 1,1, B, n0, 64); STAGEH(0,     1,1, A, m0, 64);
  VMW(8);
  BAR();

#pragma unroll 1
  for (int j = 0; j < NIT-1; ++j) {
    const int kA = (2*j+2)*64, kB = (2*j+3)*64;
    LOADA(0,0); LOADB(bF0, 0,0);
    BAR(); MM(0,0,bF0); BAR();
    LOADB(bF1, 0,1);
    STAGEH(0, 0,0, A, m0, kA); STAGEH(65536, 0,0, B, n0, kA);
    BAR(); MM(0,1,bF1); BAR();
    LOADA(0,1);
    STAGEH(65536, 0,1, B, n0, kA);
    BAR(); MM(1,0,bF0); BAR();
    STAGEH(0, 0,1, A, m0, kA);
    VMW(8);
    BAR(); MM(1,1,bF1); BAR();
    LOADA(1,0); LOADB(bF0, 1,0);
    BAR(); MM(0,0,bF0); BAR();
    LOADB(bF1, 1,1);
    STAGEH(0, 1,0, A, m0, kB); STAGEH(65536, 1,0, B, n0, kB);
    BAR(); MM(0,1,bF1); BAR();
    LOADA(1,1);
    STAGEH(65536, 1,1, B, n0, kB);
    BAR(); MM(1,0,bF0); BAR();
    STAGEH(0, 1,1, A, m0, kB);
    VMW(8);
    BAR(); MM(1,1,bF1); BAR();
  }
  LOADA(0,0); LOADB(bF0, 0,0);
  BAR(); MM(0,0,bF0); BAR();
  LOADB(bF1, 0,1);
  BAR(); MM(0,1,bF1); BAR();
  LOADA(0,1);
  BAR(); MM(1,0,bF0); BAR();
  VMW(0);
  BAR(); MM(1,1,bF1); BAR();
  LOADA(1,0); LOADB(bF0, 1,0);
  BAR(); MM(0,0,bF0); BAR();
  LOADB(bF1, 1,1);
  BAR(); MM(0,1,bF1); BAR();
  LOADA(1,1);
  BAR(); MM(1,0,bF0); BAR();
  BAR(); MM(1,1,bF1); BAR();

  const int crow = lhi * 4;
#pragma unroll
  for (int mh = 0; mh < 2; ++mh)
#pragma unroll
    for (int nh = 0; nh < 2; ++nh)
#pragma unroll
      for (int m_ = 0; m_ < 4; ++m_)
#pragma unroll
        for (int n_ = 0; n_ < 2; ++n_) {
          float* cp = C + (size_t)(m0 + mh*128 + wm*64 + m_*16 + crow) * DIM
                        + (n0 + nh*128 + wn*32 + n_*16 + l15);
#pragma unroll
          for (int j2 = 0; j2 < 4; ++j2)
            cp[(size_t)j2 * DIM] = acc[mh][nh][m_][n_][j2];
        }
}

// ---------------- launch -------------------------------------------------------
extern "C" void kernel_launch(void* const* d_in, const int* in_sizes, int n_in,
                              void* d_out, int out_size, void* d_ws, size_t ws_size,
                              hipStream_t stream) {
  const float* x    = (const float*)d_in[0];
  const float* qry  = (const float*)d_in[1];
  const float* kvs  = (const float*)d_in[2];
  const float* wout = (const float*)d_in[3];
  float* out = (float*)d_out;

  char* ws = (char*)d_ws;
  size_t off = 0;
  uint4* spec = (uint4*)(ws + off);                     // 67.4 MB
  off += (size_t)ROWS * SPEC_STRIDE * sizeof(uint4);
  off = (off + 255) & ~(size_t)255;
  unsigned short* G = (unsigned short*)(ws + off);      // 67 MB (spectral A)
  off += (size_t)ROWS * DIM * sizeof(unsigned short);
  off = (off + 255) & ~(size_t)255;
  unsigned short* H = (unsigned short*)(ws + off);      // 8.4 MB (spectral W)
  off += (size_t)DIM * DIM * sizeof(unsigned short);
  off = (off + 255) & ~(size_t)255;
  float2* partial = (float2*)(ws + off);                // 8.4 MB
  off += (size_t)BATCH * NSC * NFREQ * sizeof(float2);
  off = (off + 255) & ~(size_t)255;
  float2* gtot = (float2*)(ws + off);                   // 0.5 MB (raw group totals)
  off += (size_t)BATCH * NGRP * NFREQ * sizeof(float2);

  hipLaunchKernelGGL(fwd_wfft,  dim3(BATCH*NSC + DIM),   dim3(256), 0, stream, x, wout, kvs, spec, partial, H);
  hipLaunchKernelGGL(scanA,     dim3(BATCH*NGRP*5),      dim3(256), 0, stream, partial, gtot);
  hipLaunchKernelGGL(inv_fused, dim3(BATCH*NSC),         dim3(256), 0, stream, spec, kvs, qry, partial, gtot, G);
  hipLaunchKernelGGL(gemm256,   dim3((ROWS/256)*(DIM/256)), dim3(512), 0, stream, G, H, out);
}